// Round 6
// baseline (124.311 us; speedup 1.0000x reference)
//
#include <hip/hip_runtime.h>

typedef unsigned short u16;
typedef __attribute__((ext_vector_type(8))) short short8;
typedef __attribute__((ext_vector_type(4))) float f32x4;

#define GLL16(g, l) __builtin_amdgcn_global_load_lds(                         \
    (const __attribute__((address_space(1))) void*)(g),                        \
    (__attribute__((address_space(3))) void*)(l), 16, 0, 0)

__device__ __forceinline__ u16 f2bf(float f) {
  union { float f; unsigned u; } v; v.f = f;
  unsigned u = v.u;
  return (u16)((u + 0x7FFFu + ((u >> 16) & 1u)) >> 16);  // RNE
}

// ---------------------------------------------------------------------------
// Kernel A: convert x -> bf16, compute fp32 router logits (W_router in LDS).
// ---------------------------------------------------------------------------
__global__ __launch_bounds__(512) void k_conv_router(
    const float* __restrict__ x, const float* __restrict__ Wr,
    u16* __restrict__ xbf, float* __restrict__ logits)
{
  __shared__ float wlds[16384];  // 8 x 2048 fp32 = 64 KB
  {
    const float4* src = (const float4*)Wr;
    float4* dst = (float4*)wlds;
    int t = threadIdx.x;
#pragma unroll
    for (int i = 0; i < 8; ++i) dst[t + i * 512] = src[t + i * 512];
  }
  __syncthreads();
  int wave = threadIdx.x >> 6, lane = threadIdx.x & 63;
  const float4* wv = (const float4*)wlds;
#pragma unroll 1
  for (int s = 0; s < 2; ++s) {
    int tok = blockIdx.x * 16 + wave * 2 + s;
    const float4* xrow = (const float4*)(x + tok * 2048);
    ushort4* orow = (ushort4*)(xbf + tok * 2048);
    float acc[8];
#pragma unroll
    for (int e = 0; e < 8; ++e) acc[e] = 0.f;
#pragma unroll 1
    for (int i = 0; i < 8; ++i) {
      float4 xv = xrow[lane + i * 64];
      ushort4 o;
      o.x = f2bf(xv.x); o.y = f2bf(xv.y);
      o.z = f2bf(xv.z); o.w = f2bf(xv.w);
      orow[lane + i * 64] = o;
#pragma unroll
      for (int e = 0; e < 8; ++e) {
        float4 b = wv[e * 512 + lane + i * 64];
        acc[e] += xv.x * b.x + xv.y * b.y + xv.z * b.z + xv.w * b.w;
      }
    }
#pragma unroll
    for (int e = 0; e < 8; ++e) {
      float v = acc[e];
#pragma unroll
      for (int off = 32; off > 0; off >>= 1) v += __shfl_xor(v, off, 64);
      acc[e] = v;
    }
    if (lane == 0) {
#pragma unroll
      for (int e = 0; e < 8; ++e) logits[tok * 8 + e] = acc[e];
    }
  }
}

// ---------------------------------------------------------------------------
// Kernel B: W_base->bf16, A_w->bf16, B_w -> BmatT [2048][64] bf16.
// ---------------------------------------------------------------------------
__global__ __launch_bounds__(256) void k_convert(
    const float* __restrict__ Wb, const float* __restrict__ Aw,
    const float* __restrict__ Bw,
    u16* __restrict__ wbf, u16* __restrict__ aabf, u16* __restrict__ bmt)
{
  int b = blockIdx.x, t = threadIdx.x;
  if (b < 1024) {
    int tid = b * 256 + t;
    const float4* src = (const float4*)Wb;
    ushort4* dst = (ushort4*)wbf;
#pragma unroll
    for (int i = 0; i < 4; ++i) {
      float4 v = src[tid + i * 262144];
      ushort4 o; o.x = f2bf(v.x); o.y = f2bf(v.y); o.z = f2bf(v.z); o.w = f2bf(v.w);
      dst[tid + i * 262144] = o;
    }
  } else if (b < 1056) {
    int tid = (b - 1024) * 256 + t;
    const float4* src = (const float4*)Aw;
    ushort4* dst = (ushort4*)aabf;
#pragma unroll
    for (int i = 0; i < 4; ++i) {
      float4 v = src[tid + i * 8192];
      ushort4 o; o.x = f2bf(v.x); o.y = f2bf(v.y); o.z = f2bf(v.z); o.w = f2bf(v.w);
      dst[tid + i * 8192] = o;
    }
  } else {
    int n = (b - 1056) * 256 + t;  // 0..2047
#pragma unroll
    for (int e = 0; e < 8; ++e) {
      const float4* src = (const float4*)(Bw + e * 16384 + n * 8);
      float4 v0 = src[0], v1 = src[1];
      ushort4 o0, o1;
      o0.x = f2bf(v0.x); o0.y = f2bf(v0.y); o0.z = f2bf(v0.z); o0.w = f2bf(v0.w);
      o1.x = f2bf(v1.x); o1.y = f2bf(v1.y); o1.z = f2bf(v1.z); o1.w = f2bf(v1.w);
      ushort4* dst = (ushort4*)(bmt + n * 64 + e * 8);
      dst[0] = o0; dst[1] = o1;
    }
  }
}

// ---------------------------------------------------------------------------
// Kernel C (fused hgemm+topk): per block, 32 tokens x full K=2048.
// h = x_bf16 @ A_all^T accumulated in MFMA regs; gates computed from logits
// in the epilogue; writes sparse gate-scaled G[8192][64] bf16 directly.
// 256 blocks x 128 thr (2 waves, wave w owns token rows w*16..w*16+15).
// ---------------------------------------------------------------------------
__global__ __launch_bounds__(128) void k_hA(
    const u16* __restrict__ xbf, const u16* __restrict__ aabf,
    const float* __restrict__ logits, u16* __restrict__ G)
{
  __shared__ u16 As[2][32 * 64];
  __shared__ u16 Bs[2][64 * 64];
  const int tid = threadIdx.x, w = tid >> 6, lane = tid & 63;
  const int fr = lane & 15, fg = lane >> 4;
  const int rl = lane >> 3;
  const int ce = ((lane & 7) ^ rl) << 3;    // swizzled source col (elems)
  const int swz = (fr & 7) << 3;
  const int colk0 = (fg * 8) ^ swz;
  const int colk1 = (32 + fg * 8) ^ swz;
  const int tokBase = blockIdx.x * 32;

  auto STAGE = [&](int s) {
    const int buf = s & 1, k0 = s * 64;
    // A: 32 rows (2 loads/wave)
    GLL16(xbf + (tokBase + w * 16 + rl) * 2048 + k0 + ce, &As[buf][(w * 16) * 64]);
    GLL16(xbf + (tokBase + w * 16 + 8 + rl) * 2048 + k0 + ce, &As[buf][(w * 16 + 8) * 64]);
    // B: 64 rows (4 loads/wave)
#pragma unroll
    for (int c = 0; c < 4; ++c)
      GLL16(aabf + (w * 32 + c * 8 + rl) * 2048 + k0 + ce, &Bs[buf][(w * 32 + c * 8) * 64]);
  };

  f32x4 acc[4];
  const f32x4 zero = {0.f, 0.f, 0.f, 0.f};
#pragma unroll
  for (int nj = 0; nj < 4; ++nj) acc[nj] = zero;

  STAGE(0);
  asm volatile("s_waitcnt vmcnt(0)" ::: "memory");
  __syncthreads();

#pragma unroll 1
  for (int t = 0; t < 32; ++t) {
    if (t < 31) STAGE(t + 1);
    const int buf = t & 1;
    short8 a[2], bfr[4][2];
    a[0] = *(const short8*)&As[buf][(w * 16 + fr) * 64 + colk0];
    a[1] = *(const short8*)&As[buf][(w * 16 + fr) * 64 + colk1];
#pragma unroll
    for (int nj = 0; nj < 4; ++nj) {
      bfr[nj][0] = *(const short8*)&Bs[buf][(nj * 16 + fr) * 64 + colk0];
      bfr[nj][1] = *(const short8*)&Bs[buf][(nj * 16 + fr) * 64 + colk1];
    }
    asm volatile("s_waitcnt lgkmcnt(0)" ::: "memory");
#pragma unroll
    for (int kk = 0; kk < 2; ++kk)
#pragma unroll
      for (int nj = 0; nj < 4; ++nj)
        acc[nj] = __builtin_amdgcn_mfma_f32_16x16x32_bf16(a[kk], bfr[nj][kk], acc[nj], 0, 0, 0);
    asm volatile("s_waitcnt vmcnt(0)" ::: "memory");
    __syncthreads();
  }

  // epilogue: gates from logits; write sparse gate-scaled G
#pragma unroll
  for (int r = 0; r < 4; ++r) {
    const int tok = tokBase + w * 16 + fg * 4 + r;
    const float* lg = logits + tok * 8;
    float la[8];
#pragma unroll
    for (int e = 0; e < 8; ++e) la[e] = lg[e];
    float v0 = la[0]; int i0 = 0;
#pragma unroll
    for (int e = 1; e < 8; ++e) { if (la[e] > v0) { v0 = la[e]; i0 = e; } }
    float v1 = -3.4e38f; int i1 = 0;
#pragma unroll
    for (int e = 0; e < 8; ++e) { if (e != i0 && la[e] > v1) { v1 = la[e]; i1 = e; } }
    float ex = expf(v1 - v0);
    float inv = 1.f / (1.f + ex);
    float gate0 = inv, gate1 = ex * inv;
#pragma unroll
    for (int nj = 0; nj < 4; ++nj) {
      const int er = nj * 16 + fr;
      const int e = er >> 3;
      const float g = (e == i0) ? gate0 : ((e == i1) ? gate1 : 0.f);
      G[tok * 64 + er] = f2bf(2.0f * g * acc[nj][r]);  // SCALE = alpha/r = 2
    }
  }
}

// ---------------------------------------------------------------------------
// Kernel E: main GEMM, 256x256, BK=64, READ-AHEAD 4-phase pipeline.
// K = 2048 (tiles 0..31) + virtual LoRA K-tile 32 (A=G, B=BmT, ld=64).
// MFMA bursts: kk OUTERMOST -> 8 independent MFMAs between same-acc reuses
// (per-acc FP order unchanged: kk0 then kk1 -> bitwise-identical output).
// ---------------------------------------------------------------------------
__global__ __launch_bounds__(512, 2) void k_main(
    const u16* __restrict__ xbf, const u16* __restrict__ wbf,
    const u16* __restrict__ G, const u16* __restrict__ BmT,
    const float* __restrict__ bias, float* __restrict__ out)
{
  __shared__ u16 lds[65536];  // A bufs: [0,32768)  B bufs: [32768,65536)
  const int tid = threadIdx.x;
  const int w = tid >> 6, lane = tid & 63;
  const int fr = lane & 15, fg = lane >> 4;
  const int wr = w >> 2, wc = w & 3;

  // XCD-aware swizzle (256 blocks, 256%8==0 -> bijective)
  const int b0 = blockIdx.x;
  const int wg = (b0 & 7) * 32 + (b0 >> 3);
  const int mBase = (wg >> 3) * 256;   // 32 m-tiles
  const int nBase = (wg & 7) * 256;    //  8 n-tiles

  // staging addressing (linear LDS dest; swizzled global source col)
  const int rl = lane >> 3;                 // 0..7
  const int ce = ((lane & 7) ^ rl) << 3;    // source col elems (XOR swizzle)
  // ds_read addressing (same XOR involution)
  const int swz = (fr & 7) << 3;
  const int colk0 = (fg * 8) ^ swz;
  const int colk1 = (32 + fg * 8) ^ swz;
  const int aOff = (wr * 128 + fr) * 64;
  const int bOff = (wc * 64 + fr) * 64;

  f32x4 acc[8][4];
  const f32x4 zero = {0.f, 0.f, 0.f, 0.f};
#pragma unroll
  for (int mi = 0; mi < 8; ++mi)
#pragma unroll
    for (int nj = 0; nj < 4; ++nj) acc[mi][nj] = zero;

  // half codes: 0=A.lo 1=A.hi 2=B.lo 3=B.hi
  auto STAGE = [&](int s, int which) {
    if (s > 32) return;
    const bool isA = (which < 2);
    const int h = which & 1;
    const u16* src; int ld, k0;
    if (s < 32) { src = isA ? xbf : wbf; ld = 2048; k0 = s * 64; }
    else        { src = isA ? G   : BmT; ld = 64;   k0 = 0;      }
    const int rb = (isA ? mBase : nBase) + h * 128 + w * 8 + rl;
    u16* dst = lds + (isA ? 0 : 32768) + (s & 1) * 16384 + h * 8192 + w * 512;
    GLL16(src + rb * ld + k0 + ce, dst);                // rows rb..    (q=0)
    GLL16(src + (rb + 64) * ld + k0 + ce, dst + 4096);  // rows rb+64.. (q=1)
  };

  short8 Aa[2][2], Ab[2][2];   // A mi-pair ping-pong
  short8 Bx[4][2], By[4][2];   // B tile ping-pong (full tile in regs)

#define LGKM(N) asm volatile("s_waitcnt lgkmcnt(" #N ")" ::: "memory")
#define VMC(N)  asm volatile("s_waitcnt vmcnt(" #N ")" ::: "memory")
#define BAR()   __builtin_amdgcn_s_barrier()

#define RDA(DST, BUF, MI0)                                                    \
  DST[0][0] = *(const short8*)((BUF) + aOff + (MI0) * 1024 + colk0);          \
  DST[0][1] = *(const short8*)((BUF) + aOff + (MI0) * 1024 + colk1);          \
  DST[1][0] = *(const short8*)((BUF) + aOff + ((MI0) + 1) * 1024 + colk0);    \
  DST[1][1] = *(const short8*)((BUF) + aOff + ((MI0) + 1) * 1024 + colk1);

#define RDB(DST, BUF, NJ0)                                                    \
  DST[(NJ0)][0] = *(const short8*)((BUF) + bOff + (NJ0) * 1024 + colk0);      \
  DST[(NJ0)][1] = *(const short8*)((BUF) + bOff + (NJ0) * 1024 + colk1);      \
  DST[(NJ0)+1][0] = *(const short8*)((BUF) + bOff + ((NJ0)+1) * 1024 + colk0);\
  DST[(NJ0)+1][1] = *(const short8*)((BUF) + bOff + ((NJ0)+1) * 1024 + colk1);

#define MFMA16(AV, BV, MI0)                                                   \
  __builtin_amdgcn_s_setprio(1);                                              \
  _Pragma("unroll")                                                           \
  for (int kk = 0; kk < 2; ++kk)                                              \
    _Pragma("unroll")                                                         \
    for (int q = 0; q < 2; ++q)                                               \
      _Pragma("unroll")                                                       \
      for (int nj = 0; nj < 4; ++nj)                                          \
        acc[(MI0) + q][nj] = __builtin_amdgcn_mfma_f32_16x16x32_bf16(         \
            AV[q][kk], BV[nj][kk], acc[(MI0) + q][nj], 0, 0, 0);              \
  __builtin_amdgcn_s_setprio(0);

  // TILE(T, P=T&1 literal, BC=cur B regs, BN=next B regs)
#define TILE(T, P, BC, BN)                                                    \
  {                                                                           \
    const u16* Acur = lds + (P) * 16384;                                      \
    const u16* Anxt = lds + (1 - (P)) * 16384;                                \
    const u16* Bnxt = lds + 32768 + (1 - (P)) * 16384;                        \
    /* p0 */                                                                  \
    STAGE((T) + 1, 0);                                                        \
    RDA(Ab, Acur, 2)                                                          \
    LGKM(4);                                                                  \
    MFMA16(Aa, BC, 0)                                                         \
    BAR();                                                                    \
    /* p1 */                                                                  \
    STAGE((T) + 1, 1);                                                        \
    RDA(Aa, Acur, 4)                                                          \
    LGKM(4);                                                                  \
    MFMA16(Ab, BC, 2)                                                         \
    VMC(4);                                                                   \
    BAR();                                                                    \
    /* p2 */                                                                  \
    STAGE((T) + 2, 2);                                                        \
    RDA(Ab, Acur, 6)                                                          \
    RDB(BN, Bnxt, 0)                                                          \
    LGKM(8);                                                                  \
    MFMA16(Aa, BC, 4)                                                         \
    if ((T) == 31) { VMC(0); } else { VMC(2); }                               \
    BAR();                                                                    \
    /* p3 */                                                                  \
    STAGE((T) + 2, 3);                                                        \
    RDA(Aa, Anxt, 0)                                                          \
    RDB(BN, Bnxt, 2)                                                          \
    LGKM(8);                                                                  \
    MFMA16(Ab, BC, 6)                                                         \
    BAR();                                                                    \
  }

  // ---- prologue: stage A0,B0,B1 (12 loads); land A0,B0; read B0 + A01(0)
  STAGE(0, 0); STAGE(0, 1); STAGE(0, 2); STAGE(0, 3);
  STAGE(1, 2); STAGE(1, 3);
  VMC(4);
  BAR();
  {
    const u16* Bb0 = lds + 32768;
    RDB(Bx, Bb0, 0)
    RDB(Bx, Bb0, 2)
    RDA(Aa, lds, 0)
  }

#pragma unroll 1
  for (int tt = 0; tt < 16; ++tt) {
    const int t0 = tt * 2;
    TILE(t0, 0, Bx, By)
    TILE(t0 + 1, 1, By, Bx)
  }

  // ---- tile 32 (LoRA): no stages, no barriers, Bcur = Bx (read at t=31 p3)
  {
    const u16* Acur = lds;  // 32&1 == 0
    RDA(Ab, Acur, 2)
    LGKM(4);
    MFMA16(Aa, Bx, 0)
    RDA(Aa, Acur, 4)
    LGKM(4);
    MFMA16(Ab, Bx, 2)
    RDA(Ab, Acur, 6)
    LGKM(4);
    MFMA16(Aa, Bx, 4)
    LGKM(0);
    MFMA16(Ab, Bx, 6)
  }

  // ---- epilogue: bias add + store
#pragma unroll
  for (int nj = 0; nj < 4; ++nj) {
    const int n = nBase + wc * 64 + nj * 16 + fr;
    const float bv = bias[n];
#pragma unroll
    for (int mi = 0; mi < 8; ++mi) {
      const int m = mBase + wr * 128 + mi * 16 + fg * 4;
#pragma unroll
      for (int r = 0; r < 4; ++r)
        out[(m + r) * 2048 + n] = acc[mi][nj][r] + bv;
    }
  }
#undef TILE
#undef MFMA16
#undef RDB
#undef RDA
#undef BAR
#undef VMC
#undef LGKM
}

// ---------------------------------------------------------------------------
extern "C" void kernel_launch(void* const* d_in, const int* in_sizes, int n_in,
                              void* d_out, int out_size, void* d_ws, size_t ws_size,
                              hipStream_t stream) {
  const float* x  = (const float*)d_in[0];   // [4,2048,2048]
  const float* Wb = (const float*)d_in[1];   // [2048,2048]
  const float* bb = (const float*)d_in[2];   // [2048]
  const float* Wr = (const float*)d_in[3];   // [8,2048]
  const float* Aw = (const float*)d_in[4];   // [8,8,2048] == [64][2048]
  const float* Bw = (const float*)d_in[5];   // [8,2048,8]

  char* ws = (char*)d_ws;
  u16*   xbf  = (u16*)  (ws + 0);            // 33,554,432 B
  u16*   wbf  = (u16*)  (ws + 33554432);     //  8,388,608 B
  u16*   aabf = (u16*)  (ws + 41943040);     //    262,144 B
  u16*   bmt  = (u16*)  (ws + 42205184);     //    262,144 B
  float* lgt  = (float*)(ws + 42467328);     //    262,144 B
  u16*   G    = (u16*)  (ws + 42729472);     //  1,048,576 B
  float* out = (float*)d_out;

  hipLaunchKernelGGL(k_conv_router, dim3(512),  dim3(512), 0, stream, x, Wr, xbf, lgt);
  hipLaunchKernelGGL(k_convert,     dim3(1064), dim3(256), 0, stream, Wb, Aw, Bw, wbf, aabf, bmt);
  hipLaunchKernelGGL(k_hA,          dim3(256),  dim3(128), 0, stream, xbf, aabf, lgt, G);
  hipLaunchKernelGGL(k_main,        dim3(256),  dim3(512), 0, stream, xbf, wbf, G, bmt, bb, out);
}

// Round 7
// 121.701 us; speedup vs baseline: 1.0215x; 1.0215x over previous
//
#include <hip/hip_runtime.h>

typedef unsigned short u16;
typedef __attribute__((ext_vector_type(8))) short short8;
typedef __attribute__((ext_vector_type(4))) float f32x4;

#define GLL16(g, l) __builtin_amdgcn_global_load_lds(                         \
    (const __attribute__((address_space(1))) void*)(g),                        \
    (__attribute__((address_space(3))) void*)(l), 16, 0, 0)

__device__ __forceinline__ u16 f2bf(float f) {
  union { float f; unsigned u; } v; v.f = f;
  unsigned u = v.u;
  return (u16)((u + 0x7FFFu + ((u >> 16) & 1u)) >> 16);  // RNE
}

// ---------------------------------------------------------------------------
// Kernel A: convert x -> bf16, compute fp32 router logits (W_router in LDS).
// ---------------------------------------------------------------------------
__global__ __launch_bounds__(512) void k_conv_router(
    const float* __restrict__ x, const float* __restrict__ Wr,
    u16* __restrict__ xbf, float* __restrict__ logits)
{
  __shared__ float wlds[16384];  // 8 x 2048 fp32 = 64 KB
  {
    const float4* src = (const float4*)Wr;
    float4* dst = (float4*)wlds;
    int t = threadIdx.x;
#pragma unroll
    for (int i = 0; i < 8; ++i) dst[t + i * 512] = src[t + i * 512];
  }
  __syncthreads();
  int wave = threadIdx.x >> 6, lane = threadIdx.x & 63;
  const float4* wv = (const float4*)wlds;
#pragma unroll 1
  for (int s = 0; s < 2; ++s) {
    int tok = blockIdx.x * 16 + wave * 2 + s;
    const float4* xrow = (const float4*)(x + tok * 2048);
    ushort4* orow = (ushort4*)(xbf + tok * 2048);
    float acc[8];
#pragma unroll
    for (int e = 0; e < 8; ++e) acc[e] = 0.f;
#pragma unroll 1
    for (int i = 0; i < 8; ++i) {
      float4 xv = xrow[lane + i * 64];
      ushort4 o;
      o.x = f2bf(xv.x); o.y = f2bf(xv.y);
      o.z = f2bf(xv.z); o.w = f2bf(xv.w);
      orow[lane + i * 64] = o;
#pragma unroll
      for (int e = 0; e < 8; ++e) {
        float4 b = wv[e * 512 + lane + i * 64];
        acc[e] += xv.x * b.x + xv.y * b.y + xv.z * b.z + xv.w * b.w;
      }
    }
#pragma unroll
    for (int e = 0; e < 8; ++e) {
      float v = acc[e];
#pragma unroll
      for (int off = 32; off > 0; off >>= 1) v += __shfl_xor(v, off, 64);
      acc[e] = v;
    }
    if (lane == 0) {
#pragma unroll
      for (int e = 0; e < 8; ++e) logits[tok * 8 + e] = acc[e];
    }
  }
}

// ---------------------------------------------------------------------------
// Kernel B: W_base->bf16, A_w->bf16, B_w -> BmatT [2048][64] bf16.
// ---------------------------------------------------------------------------
__global__ __launch_bounds__(256) void k_convert(
    const float* __restrict__ Wb, const float* __restrict__ Aw,
    const float* __restrict__ Bw,
    u16* __restrict__ wbf, u16* __restrict__ aabf, u16* __restrict__ bmt)
{
  int b = blockIdx.x, t = threadIdx.x;
  if (b < 1024) {
    int tid = b * 256 + t;
    const float4* src = (const float4*)Wb;
    ushort4* dst = (ushort4*)wbf;
#pragma unroll
    for (int i = 0; i < 4; ++i) {
      float4 v = src[tid + i * 262144];
      ushort4 o; o.x = f2bf(v.x); o.y = f2bf(v.y); o.z = f2bf(v.z); o.w = f2bf(v.w);
      dst[tid + i * 262144] = o;
    }
  } else if (b < 1056) {
    int tid = (b - 1024) * 256 + t;
    const float4* src = (const float4*)Aw;
    ushort4* dst = (ushort4*)aabf;
#pragma unroll
    for (int i = 0; i < 4; ++i) {
      float4 v = src[tid + i * 8192];
      ushort4 o; o.x = f2bf(v.x); o.y = f2bf(v.y); o.z = f2bf(v.z); o.w = f2bf(v.w);
      dst[tid + i * 8192] = o;
    }
  } else {
    int n = (b - 1056) * 256 + t;  // 0..2047
#pragma unroll
    for (int e = 0; e < 8; ++e) {
      const float4* src = (const float4*)(Bw + e * 16384 + n * 8);
      float4 v0 = src[0], v1 = src[1];
      ushort4 o0, o1;
      o0.x = f2bf(v0.x); o0.y = f2bf(v0.y); o0.z = f2bf(v0.z); o0.w = f2bf(v0.w);
      o1.x = f2bf(v1.x); o1.y = f2bf(v1.y); o1.z = f2bf(v1.z); o1.w = f2bf(v1.w);
      ushort4* dst = (ushort4*)(bmt + n * 64 + e * 8);
      dst[0] = o0; dst[1] = o1;
    }
  }
}

// ---------------------------------------------------------------------------
// Kernel C: h partials. h_all[m][64] = x_bf16 @ A_all^T, split-K (8 slices).
// ---------------------------------------------------------------------------
__global__ __launch_bounds__(256) void k_hgemm(
    const u16* __restrict__ xbf, const u16* __restrict__ aabf,
    float* __restrict__ P)
{
  __shared__ u16 As[256 * 64];
  __shared__ u16 Bs[64 * 64];
  int t = threadIdx.x, wave = t >> 6, lane = t & 63;
  int mBase = blockIdx.x * 256;
  int ks = blockIdx.y;
  int fr = lane & 15, fg = lane >> 4;
  int lrow = lane >> 3, lcol = (lane & 7) * 8;
  f32x4 zero = {0.f, 0.f, 0.f, 0.f};
  f32x4 acc[4][4];
#pragma unroll
  for (int i = 0; i < 4; ++i)
#pragma unroll
    for (int j = 0; j < 4; ++j) acc[i][j] = zero;
#pragma unroll 1
  for (int it = 0; it < 4; ++it) {
    int k0 = ks * 256 + it * 64;
    __syncthreads();
#pragma unroll
    for (int cc = 0; cc < 8; ++cc) {
      int c = wave * 8 + cc;
      GLL16(xbf + (mBase + c * 8 + lrow) * 2048 + k0 + lcol, &As[c * 512]);
    }
#pragma unroll
    for (int cc = 0; cc < 2; ++cc) {
      int c = wave * 2 + cc;
      GLL16(aabf + (c * 8 + lrow) * 2048 + k0 + lcol, &Bs[c * 512]);
    }
    __syncthreads();
#pragma unroll
    for (int kk = 0; kk < 2; ++kk) {
      short8 a[4], bfr[4];
#pragma unroll
      for (int i = 0; i < 4; ++i)
        a[i] = *(const short8*)&As[(wave * 64 + i * 16 + fr) * 64 + kk * 32 + fg * 8];
#pragma unroll
      for (int j = 0; j < 4; ++j)
        bfr[j] = *(const short8*)&Bs[(j * 16 + fr) * 64 + kk * 32 + fg * 8];
#pragma unroll
      for (int i = 0; i < 4; ++i)
#pragma unroll
        for (int j = 0; j < 4; ++j)
          acc[i][j] = __builtin_amdgcn_mfma_f32_16x16x32_bf16(a[i], bfr[j], acc[i][j], 0, 0, 0);
    }
  }
#pragma unroll
  for (int i = 0; i < 4; ++i)
#pragma unroll
    for (int j = 0; j < 4; ++j)
#pragma unroll
      for (int r = 0; r < 4; ++r) {
        int m = mBase + wave * 64 + i * 16 + fg * 4 + r;
        int n = j * 16 + fr;
        P[(ks * 8192 + m) * 64 + n] = acc[i][j][r];
      }
}

// ---------------------------------------------------------------------------
// Kernel D: per-token top-2 + softmax gates; reduce split-K partials; emit
// sparse gate-scaled G[8192][64] bf16.
// ---------------------------------------------------------------------------
__global__ __launch_bounds__(256) void k_topk(
    const float* __restrict__ logits, const float* __restrict__ P,
    u16* __restrict__ G)
{
  int t = threadIdx.x, wave = t >> 6, lane = t & 63;
  int tok = blockIdx.x * 4 + wave;
  const float* lg = logits + tok * 8;
  float la[8];
#pragma unroll
  for (int e = 0; e < 8; ++e) la[e] = lg[e];
  float v0 = la[0]; int i0 = 0;
#pragma unroll
  for (int e = 1; e < 8; ++e) { if (la[e] > v0) { v0 = la[e]; i0 = e; } }
  float v1 = -3.4e38f; int i1 = 0;
#pragma unroll
  for (int e = 0; e < 8; ++e) { if (e != i0 && la[e] > v1) { v1 = la[e]; i1 = e; } }
  float ex = expf(v1 - v0);
  float inv = 1.f / (1.f + ex);
  float gate0 = inv, gate1 = ex * inv;
  int e = lane >> 3;
  float h = 0.f;
#pragma unroll
  for (int ks = 0; ks < 8; ++ks) h += P[(ks * 8192 + tok) * 64 + lane];
  float g = (e == i0) ? gate0 : ((e == i1) ? gate1 : 0.f);
  G[tok * 64 + lane] = f2bf(2.0f * g * h);  // SCALE = alpha/r = 2
}

// ---------------------------------------------------------------------------
// Kernel E: main GEMM, 256x256, BK=64, m201-faithful QUADRANT schedule.
// K = 2048 (tiles 0..31) + virtual LoRA K-tile 32 (A=G, B=BmT, ld=64).
// Phase p = one C-quadrant (mi-quad x nj-pair), 16 MFMA, operand REUSE:
//   P0: rd A mi0-3 (8) + B nj0-1 (4) | lgkm(8) | bar | lgkm(0) | MFMA Q00
//   P1: rd B nj2-3 (4)               |         | bar | lgkm(0) | MFMA Q01
//   P2: rd A mi4-7 (8) | stage (t+2).Blo,.Bhi | bar | lgkm(0) | MFMA Q10
//   P3:                | stage (t+2).Alo,.Ahi | bar |         | MFMA Q11
//                                              | vmcnt(6) [t=31: 0] | bar
// Read profile 12/4/8/0 (24 total). ONE vmcnt per tile, N=6 = 2 loads x
// 3 half-tiles in flight (template-exact). Overwrite-safety: (t+2).B staged
// after P1-end bar (all B(t) reads lgkm-retired CU-wide at P1's lgkm(0));
// (t+2).A after P2-end bar. Ledger: at tile end 14 outstanding -> vmcnt(6)
// retires tile (t+1) fully + (t+2).Blo.
// ---------------------------------------------------------------------------
__global__ __launch_bounds__(512, 2) void k_main(
    const u16* __restrict__ xbf, const u16* __restrict__ wbf,
    const u16* __restrict__ G, const u16* __restrict__ BmT,
    const float* __restrict__ bias, float* __restrict__ out)
{
  __shared__ u16 lds[65536];  // A bufs: [0,32768)  B bufs: [32768,65536)
  const int tid = threadIdx.x;
  const int w = tid >> 6, lane = tid & 63;
  const int fr = lane & 15, fg = lane >> 4;
  const int wr = w >> 2, wc = w & 3;

  // XCD-aware swizzle (256 blocks, 256%8==0 -> bijective)
  const int b0 = blockIdx.x;
  const int wg = (b0 & 7) * 32 + (b0 >> 3);
  const int mBase = (wg >> 3) * 256;   // 32 m-tiles
  const int nBase = (wg & 7) * 256;    //  8 n-tiles

  // staging addressing (linear LDS dest; swizzled global source col)
  const int rl = lane >> 3;                 // 0..7
  const int ce = ((lane & 7) ^ rl) << 3;    // source col elems (XOR swizzle)
  // ds_read addressing (same XOR involution)
  const int swz = (fr & 7) << 3;
  const int colk0 = (fg * 8) ^ swz;
  const int colk1 = (32 + fg * 8) ^ swz;
  const int aOff = (wr * 128 + fr) * 64;
  const int bOff = (wc * 64 + fr) * 64;

  f32x4 acc[8][4];
  const f32x4 zero = {0.f, 0.f, 0.f, 0.f};
#pragma unroll
  for (int mi = 0; mi < 8; ++mi)
#pragma unroll
    for (int nj = 0; nj < 4; ++nj) acc[mi][nj] = zero;

  // half codes: 0=A.lo 1=A.hi 2=B.lo 3=B.hi
  auto STAGE = [&](int s, int which) {
    if (s > 32) return;
    const bool isA = (which < 2);
    const int h = which & 1;
    const u16* src; int ld, k0;
    if (s < 32) { src = isA ? xbf : wbf; ld = 2048; k0 = s * 64; }
    else        { src = isA ? G   : BmT; ld = 64;   k0 = 0;      }
    const int rb = (isA ? mBase : nBase) + h * 128 + w * 8 + rl;
    u16* dst = lds + (isA ? 0 : 32768) + (s & 1) * 16384 + h * 8192 + w * 512;
    GLL16(src + rb * ld + k0 + ce, dst);                // rows rb..    (q=0)
    GLL16(src + (rb + 64) * ld + k0 + ce, dst + 4096);  // rows rb+64.. (q=1)
  };

#define LGKM(N) asm volatile("s_waitcnt lgkmcnt(" #N ")" ::: "memory")
#define VMC(N)  asm volatile("s_waitcnt vmcnt(" #N ")" ::: "memory")
#define BAR()   __builtin_amdgcn_s_barrier()

#define RDA4(DST, BUF, MI0)                                                   \
  _Pragma("unroll")                                                           \
  for (int q = 0; q < 4; ++q) {                                               \
    DST[q][0] = *(const short8*)((BUF) + aOff + ((MI0) + q) * 1024 + colk0);  \
    DST[q][1] = *(const short8*)((BUF) + aOff + ((MI0) + q) * 1024 + colk1);  \
  }

#define RDB2(NJ0)                                                             \
  Bv[(NJ0)][0]     = *(const short8*)(Bbuf + bOff + (NJ0) * 1024 + colk0);    \
  Bv[(NJ0)][1]     = *(const short8*)(Bbuf + bOff + (NJ0) * 1024 + colk1);    \
  Bv[(NJ0) + 1][0] = *(const short8*)(Bbuf + bOff + ((NJ0)+1) * 1024 + colk0);\
  Bv[(NJ0) + 1][1] = *(const short8*)(Bbuf + bOff + ((NJ0)+1) * 1024 + colk1);

#define MFMAQ(AV, ACCB, NJ0)                                                  \
  __builtin_amdgcn_s_setprio(1);                                              \
  _Pragma("unroll")                                                           \
  for (int kk = 0; kk < 2; ++kk)                                              \
    _Pragma("unroll")                                                         \
    for (int q = 0; q < 4; ++q)                                               \
      _Pragma("unroll")                                                       \
      for (int nj = 0; nj < 2; ++nj)                                          \
        acc[(ACCB) + q][(NJ0) + nj] =                                         \
            __builtin_amdgcn_mfma_f32_16x16x32_bf16(                          \
                AV[q][kk], Bv[(NJ0) + nj][kk],                                \
                acc[(ACCB) + q][(NJ0) + nj], 0, 0, 0);                        \
  __builtin_amdgcn_s_setprio(0);

  // ---- prologue: stage tile0 + tile1 (B.lo,B.hi,A.lo,A.hi each; 16 loads)
  STAGE(0, 2); STAGE(0, 3); STAGE(0, 0); STAGE(0, 1);
  STAGE(1, 2); STAGE(1, 3); STAGE(1, 0); STAGE(1, 1);
  VMC(8);   // retire tile0's 8 loads; tile1's 8 stay in flight
  BAR();

#pragma unroll 1
  for (int t = 0; t < 33; ++t) {
    const u16* Abuf = lds + (t & 1) * 16384;
    const u16* Bbuf = lds + 32768 + (t & 1) * 16384;
    short8 A03[4][2], A47[4][2], Bv[4][2];
    // ---- P0: A mi0-3 + B nj0-1 (12 reads)
    RDA4(A03, Abuf, 0)
    RDB2(0)
    LGKM(8);
    BAR();
    LGKM(0);
    MFMAQ(A03, 0, 0)
    BAR();
    // ---- P1: B nj2-3 (4 reads)
    RDB2(2)
    BAR();
    LGKM(0);
    MFMAQ(A03, 0, 2)
    BAR();
    // ---- P2: A mi4-7 (8 reads) + stage (t+2).B
    RDA4(A47, Abuf, 4)
    STAGE(t + 2, 2); STAGE(t + 2, 3);
    BAR();
    LGKM(0);
    MFMAQ(A47, 4, 0)
    BAR();
    // ---- P3: stage (t+2).A ; no reads
    STAGE(t + 2, 0); STAGE(t + 2, 1);
    BAR();
    MFMAQ(A47, 4, 2)
    if (t < 31)       { VMC(6); }
    else if (t == 31) { VMC(0); }
    BAR();
  }

  // ---- epilogue: bias add + store
#pragma unroll
  for (int nj = 0; nj < 4; ++nj) {
    const int n = nBase + wc * 64 + nj * 16 + fr;
    const float bv = bias[n];
#pragma unroll
    for (int mi = 0; mi < 8; ++mi) {
      const int m = mBase + wr * 128 + mi * 16 + fg * 4;
#pragma unroll
      for (int r = 0; r < 4; ++r)
        out[(m + r) * 2048 + n] = acc[mi][nj][r] + bv;
    }
  }
#undef MFMAQ
#undef RDB2
#undef RDA4
#undef BAR
#undef VMC
#undef LGKM
}

// ---------------------------------------------------------------------------
extern "C" void kernel_launch(void* const* d_in, const int* in_sizes, int n_in,
                              void* d_out, int out_size, void* d_ws, size_t ws_size,
                              hipStream_t stream) {
  const float* x  = (const float*)d_in[0];   // [4,2048,2048]
  const float* Wb = (const float*)d_in[1];   // [2048,2048]
  const float* bb = (const float*)d_in[2];   // [2048]
  const float* Wr = (const float*)d_in[3];   // [8,2048]
  const float* Aw = (const float*)d_in[4];   // [8,8,2048] == [64][2048]
  const float* Bw = (const float*)d_in[5];   // [8,2048,8]

  char* ws = (char*)d_ws;
  u16*   xbf  = (u16*)  (ws + 0);            // 33,554,432 B
  u16*   wbf  = (u16*)  (ws + 33554432);     //  8,388,608 B
  u16*   aabf = (u16*)  (ws + 41943040);     //    262,144 B
  u16*   bmt  = (u16*)  (ws + 42205184);     //    262,144 B
  float* lgt  = (float*)(ws + 42467328);     //    262,144 B
  u16*   G    = (u16*)  (ws + 42729472);     //  1,048,576 B
  // h-partials [8][8192][64] f32 live in d_out; fully consumed by k_topk
  // before k_main overwrites all of d_out. Same-stream ordering.
  float* P   = (float*)d_out;
  float* out = (float*)d_out;

  hipLaunchKernelGGL(k_conv_router, dim3(512),   dim3(512), 0, stream, x, Wr, xbf, lgt);
  hipLaunchKernelGGL(k_convert,     dim3(1064),  dim3(256), 0, stream, Wb, Aw, Bw, wbf, aabf, bmt);
  hipLaunchKernelGGL(k_hgemm,       dim3(32, 8), dim3(256), 0, stream, xbf, aabf, P);
  hipLaunchKernelGGL(k_topk,        dim3(2048),  dim3(256), 0, stream, lgt, P, G);
  hipLaunchKernelGGL(k_main,        dim3(256),   dim3(512), 0, stream, xbf, wbf, G, bmt, bb, out);
}